// Round 2
// baseline (81.746 us; speedup 1.0000x reference)
//
#include <hip/hip_runtime.h>
#include <math.h>

#define BB 512
#define CC 256
typedef unsigned long long u64;

__device__ inline float wave_sum(float v) {
    #pragma unroll
    for (int off = 32; off > 0; off >>= 1) v += __shfl_down(v, off, 64);
    return v;
}
__device__ inline float wave_max(float v) {
    #pragma unroll
    for (int off = 32; off > 0; off >>= 1) v = fmaxf(v, __shfl_down(v, off, 64));
    return v;
}

// ---------------- Kernel 1: pack concept bit-planes + masked BCE partials ----
// bitsP layout: bitsP[w*BB + i] = bits for concepts [64w, 64w+63] of row i
// (plane-major so K2's per-j loads are coalesced).
// Also zeroes the K2 completion counter (runs strictly before K2 in stream).
__global__ __launch_bounds__(256) void pack_bce_kernel(
        const int* __restrict__ mc, const float* __restrict__ cl,
        u64* __restrict__ bitsP, float* __restrict__ bce_out,
        float* __restrict__ msk_out, int* __restrict__ counter) {
    int i = blockIdx.x, tid = threadIdx.x;
    int wave = tid >> 6, lane = tid & 63;

    if (i == 0 && tid == 0) *counter = 0;

    int c = mc[i * CC + tid];
    u64 ballot = __ballot(c == 1);
    if (lane == 0) bitsP[wave * BB + i] = ballot;

    float x = cl[i * CC + tid];
    float mask = (c != -1) ? 1.0f : 0.0f;
    float t = (c == 1) ? 1.0f : 0.0f;
    float bce = (fmaxf(x, 0.0f) - x * t + log1pf(__expf(-fabsf(x)))) * mask;

    __shared__ float red[4][2];
    float wb = wave_sum(bce), wm = wave_sum(mask);
    if (lane == 0) { red[wave][0] = wb; red[wave][1] = wm; }
    __syncthreads();
    if (tid == 0) {
        bce_out[i] = red[0][0] + red[1][0] + red[2][0] + red[3][0];
        msk_out[i] = red[0][1] + red[1][1] + red[2][1] + red[3][1];
    }
}

// ---------------- Kernel 2: one block per row, fused finalize ----------------
__global__ __launch_bounds__(512) void row_kernel(
        const float* __restrict__ lpi, const float* __restrict__ lpt,
        const float* __restrict__ cis, const u64* __restrict__ bitsP,
        float* __restrict__ contrib, const float* __restrict__ bce,
        const float* __restrict__ msk, int* __restrict__ counter,
        float* __restrict__ out) {
    int i = blockIdx.x, tid = threadIdx.x;
    int wave = tid >> 6, lane = tid & 63;
    __shared__ float red[8][8];
    __shared__ int last_flag;

    // own-row masks (uniform address -> scalar loads)
    u64 m0 = bitsP[0 * BB + i], m1 = bitsP[1 * BB + i];
    u64 m2 = bitsP[2 * BB + i], m3 = bitsP[3 * BB + i];

    int j = tid;
    u64 b0 = bitsP[0 * BB + j], b1 = bitsP[1 * BB + j];
    u64 b2 = bitsP[2 * BB + j], b3 = bitsP[3 * BB + j];
    int inter = __popcll(m0 & b0) + __popcll(m1 & b1) + __popcll(m2 & b2) + __popcll(m3 & b3);
    int uni   = __popcll(m0 | b0) + __popcll(m1 | b1) + __popcll(m2 | b2) + __popcll(m3 | b3);
    float a = (uni > 0) ? (5.0f * (float)inter / (float)uni) : 0.0f;  // sim/T

    size_t off = (size_t)i * BB + j;
    float x0 = lpi[off], x1 = lpt[off], x2 = cis[off];

    // ---- phase 1: 4 independent maxes, one barrier ----
    float mv[4] = { a, x0, x1, x2 };
    #pragma unroll
    for (int k = 0; k < 4; ++k) {
        float w = wave_max(mv[k]);
        if (lane == 0) red[wave][k] = w;
    }
    __syncthreads();
    float M[4];
    #pragma unroll
    for (int k = 0; k < 4; ++k) {
        float m = red[0][k];
        #pragma unroll
        for (int w = 1; w < 8; ++w) m = fmaxf(m, red[w][k]);
        M[k] = m;
    }
    __syncthreads();   // red reuse

    // ---- phase 2: 8 independent sums, one barrier ----
    float e = __expf(a - M[0]);
    float sv[8] = { e, e * a,
                    __expf(x0 - M[1]), e * x0,
                    __expf(x1 - M[2]), e * x1,
                    __expf(x2 - M[3]), e * x2 };
    #pragma unroll
    for (int k = 0; k < 8; ++k) {
        float w = wave_sum(sv[k]);
        if (lane == 0) red[wave][k] = w;
    }
    __syncthreads();
    float S[8];
    #pragma unroll
    for (int k = 0; k < 8; ++k) {
        float s = red[0][k];
        #pragma unroll
        for (int w = 1; w < 8; ++w) s += red[w][k];
        S[k] = s;
    }

    if (tid == 0) {
        float Z = S[0], invZ = 1.0f / Z, lZ = logf(Z);
        float ent = S[1] * invZ - M[0] - lZ;              // sum t*log t
        float ci  = S[3] * invZ - M[1] - logf(S[2]);      // sum t*log_softmax(lpi)
        float ct  = S[5] * invZ - M[2] - logf(S[4]);
        float cc  = S[7] * invZ - M[3] - logf(S[6]);
        // clip = ((ENT-CI)+(ENT-CT))/(2B); + 0.2*(ENT-CC)/B
        float ctr = (2.0f * ent - ci - ct) * (0.5f / (float)BB)
                  + 0.2f * (ent - cc) * (1.0f / (float)BB);
        contrib[i] = ctr;
        __threadfence();                                   // release
        int old = atomicAdd(counter, 1);
        last_flag = (old == BB - 1);
    }
    __syncthreads();

    if (last_flag) {
        __threadfence();                                   // acquire
        float c  = contrib[tid];
        float b  = bce[tid];
        float m  = msk[tid];
        __syncthreads();   // red reuse
        float v[3] = { c, b, m };
        #pragma unroll
        for (int k = 0; k < 3; ++k) {
            float w = wave_sum(v[k]);
            if (lane == 0) red[wave][k] = w;
        }
        __syncthreads();
        if (tid == 0) {
            float C = 0.0f, Bs = 0.0f, Ms = 0.0f;
            #pragma unroll
            for (int w = 0; w < 8; ++w) { C += red[w][0]; Bs += red[w][1]; Ms += red[w][2]; }
            out[0] = C + 0.2f * (Bs / (Ms + 1e-8f));
        }
    }
}

extern "C" void kernel_launch(void* const* d_in, const int* in_sizes, int n_in,
                              void* d_out, int out_size, void* d_ws, size_t ws_size,
                              hipStream_t stream) {
    const float* lpi = (const float*)d_in[0];   // logits_per_image [512,512]
    const float* lpt = (const float*)d_in[1];   // logits_per_text  [512,512]
    const float* cl  = (const float*)d_in[2];   // concepts_logits  [512,256]
    const float* cis = (const float*)d_in[3];   // concepts_image_similarity [512,512]
    const int*   mc  = (const int*)d_in[4];     // medical_concepts [512,256]

    char* ws = (char*)d_ws;
    u64*   bitsP   = (u64*)ws;                     // 4*512*8 = 16384 B
    float* bce     = (float*)(ws + 16384);         // 512*4
    float* msk     = bce + BB;                     // 512*4
    float* contrib = msk + BB;                     // 512*4
    int*   counter = (int*)(contrib + BB);         // 4 B

    float* out = (float*)d_out;

    pack_bce_kernel<<<BB, CC, 0, stream>>>(mc, cl, bitsP, bce, msk, counter);
    row_kernel<<<BB, 512, 0, stream>>>(lpi, lpt, cis, bitsP, contrib, bce, msk, counter, out);
}